// Round 8
// baseline (589.887 us; speedup 1.0000x reference)
//
#include <hip/hip_runtime.h>

// ---------------------------------------------------------------------------
// RoutingGNN: 2-layer GCN (sym-norm, self-loops) + linear head.
// Round 8: per-node gather waves were latency-bound (short dependent chains,
// 19 cross-lane ops/node). New structure: per-BUCKET edge streaming with LDS
// accumulators (128 nodes/bucket, acc init = self-loop term, LDS atomicAdd
// per edge). Kills per-node CSR entirely (no col, no counting sort, no
// rowptr); the single-block scan becomes a parallel transposed 2-level scan.
//   k_hist  : per-block bucket histograms -> part_T[bucket][blk] (transposed)
//   k_scanA : 1 wave/bucket: scan 256 partials (int4 + shfl) -> btot
//   k_scanB : 1 block: exclusive scan of bucket totals -> bbase
//   k_binA2 : bin edges via block-private LDS cursors -> bucket-ordered bpair
//   k_dis   : per bucket: LDS count -> dis; xs = x*dis
//   k_l1    : per bucket: stream edges, LDS acc8 += xs[src]; W1+relu+W2 -> g
//   k_l2    : per bucket: stream edges, LDS acc32 += g[src]; combine+head->out
// ---------------------------------------------------------------------------

#define NBLK 256
#define SHIFT 7          // 128 nodes/bucket; n <= 131072 -> <= 1024 buckets
#define BMASK 127
#define MAXB 1024

// per-block bucket histogram -> part_T[bucket*NBLK + blk]  (no global atomics)
__global__ void k_hist(const int* __restrict__ dst, int* __restrict__ part, int E) {
    __shared__ int hist[MAXB];
    int t = threadIdx.x;           // 256
    for (int i = t; i < MAXB; i += 256) hist[i] = 0;
    __syncthreads();
    int E4 = E >> 2;
    int chunk4 = (E4 + NBLK - 1) / NBLK;
    int b = blockIdx.x;
    int s4 = b * chunk4;
    int e4 = min(s4 + chunk4, E4);
    const int4* dst4 = (const int4*)dst;
    for (int i = s4 + t; i < e4; i += 256) {
        int4 d = dst4[i];
        atomicAdd(&hist[d.x >> SHIFT], 1);
        atomicAdd(&hist[d.y >> SHIFT], 1);
        atomicAdd(&hist[d.z >> SHIFT], 1);
        atomicAdd(&hist[d.w >> SHIFT], 1);
    }
    if (b == NBLK - 1) {
        for (int e = (E4 << 2) + t; e < E; e += 256)
            atomicAdd(&hist[dst[e] >> SHIFT], 1);
    }
    __syncthreads();
    for (int i = t; i < MAXB; i += 256)
        part[(size_t)i * NBLK + b] = hist[i];
}

// one wave per bucket: exclusive scan of its 256 partials (contiguous row);
// bucket total -> btot
__global__ void k_scanA(int* __restrict__ part, int* __restrict__ btot, int nbuck) {
    int t = threadIdx.x;           // 256 = 4 waves
    int b = blockIdx.x * 4 + (t >> 6);
    if (b >= nbuck) return;
    int lane = t & 63;
    int4* p4 = (int4*)(part + (size_t)b * NBLK);
    int4 v = p4[lane];
    int ls = v.x + v.y + v.z + v.w;
    int s = ls;
#pragma unroll
    for (int off = 1; off < 64; off <<= 1) {
        int u = __shfl_up(s, off, 64);
        if (lane >= off) s += u;
    }
    int base = s - ls;             // exclusive
    int4 o;
    o.x = base;
    o.y = base + v.x;
    o.z = o.y + v.y;
    o.w = o.z + v.z;
    p4[lane] = o;
    if (lane == 63) btot[b] = s;
}

// single block, 1024 thr: exclusive scan of bucket totals -> bbase
__global__ void k_scanB(const int* __restrict__ btot, int* __restrict__ bbase,
                        int nbuck, int E) {
    __shared__ int tmp[MAXB];
    int t = threadIdx.x;
    int v = (t < nbuck) ? btot[t] : 0;
    tmp[t] = v;
    __syncthreads();
    for (int off = 1; off < MAXB; off <<= 1) {
        int add = (t >= off) ? tmp[t - off] : 0;
        __syncthreads();
        tmp[t] += add;
        __syncthreads();
    }
    bbase[t] = tmp[t] - v;
    if (t == MAXB - 1) bbase[MAXB] = E;
}

// bin edges into bucket-ordered packed words via block-private LDS cursors
__global__ void k_binA2(const int* __restrict__ src, const int* __restrict__ dst,
                        const int* __restrict__ part, const int* __restrict__ bbase,
                        int* __restrict__ bpair, int E) {
    __shared__ int cur[MAXB];
    int t = threadIdx.x;           // 512
    int b = blockIdx.x;
    cur[t]       = part[(size_t)t * NBLK + b] + bbase[t];
    cur[t + 512] = part[(size_t)(t + 512) * NBLK + b] + bbase[t + 512];
    __syncthreads();
    int E4 = E >> 2;
    int chunk4 = (E4 + NBLK - 1) / NBLK;
    int s4 = b * chunk4;
    int e4 = min(s4 + chunk4, E4);
    const int4* src4 = (const int4*)src;
    const int4* dst4 = (const int4*)dst;
    for (int i = s4 + t; i < e4; i += 512) {
        int4 s = src4[i];
        int4 d = dst4[i];
        int p0 = atomicAdd(&cur[d.x >> SHIFT], 1);
        bpair[p0] = (s.x << SHIFT) | (d.x & BMASK);
        int p1 = atomicAdd(&cur[d.y >> SHIFT], 1);
        bpair[p1] = (s.y << SHIFT) | (d.y & BMASK);
        int p2 = atomicAdd(&cur[d.z >> SHIFT], 1);
        bpair[p2] = (s.z << SHIFT) | (d.z & BMASK);
        int p3 = atomicAdd(&cur[d.w >> SHIFT], 1);
        bpair[p3] = (s.w << SHIFT) | (d.w & BMASK);
    }
    if (b == NBLK - 1) {
        for (int e = (E4 << 2) + t; e < E; e += 512) {
            int sv = src[e], dv = dst[e];
            int p = atomicAdd(&cur[dv >> SHIFT], 1);
            bpair[p] = (sv << SHIFT) | (dv & BMASK);
        }
    }
}

// one block per bucket: indegree count -> dis; xs = x * dis
__global__ void k_dis(const int* __restrict__ bpair, const int* __restrict__ bbase,
                      const float* __restrict__ x, float* __restrict__ dis,
                      float* __restrict__ xs, int n) {
    __shared__ int cnt[128];
    __shared__ float sdis[128];
    int b = blockIdx.x, t = threadIdx.x;   // 256
    int start = bbase[b], end = bbase[b + 1];
    if (t < 128) cnt[t] = 0;
    __syncthreads();
    for (int i = start + t; i < end; i += 256)
        atomicAdd(&cnt[bpair[i] & BMASK], 1);
    __syncthreads();
    if (t < 128) {
        int v = (b << SHIFT) + t;
        if (v < n) {
            float dv = rsqrtf(1.0f + (float)cnt[t]);
            dis[v] = dv;
            sdis[t] = dv;
        }
    }
    __syncthreads();
    int gbase = (b << SHIFT) * 8;
    int n8 = n * 8;
    for (int i = t; i < 1024; i += 256) {
        int gi = gbase + i;
        if (gi < n8) xs[gi] = x[gi] * sdis[i >> 3];
    }
}

// layer 1: per bucket, stream edges into LDS acc8 (init = self xs);
// then h = relu(dis*(acc8@W1)+b1); g = dis*(h@W2)
__global__ void k_l1(const int* __restrict__ bpair, const int* __restrict__ bbase,
                     const float* __restrict__ xs, const float* __restrict__ dis,
                     const float* __restrict__ W1, const float* __restrict__ b1,
                     const float* __restrict__ W2, float* __restrict__ g, int n) {
    __shared__ float sW1[256];
    __shared__ float sW2[1024];
    __shared__ float acc8[128][9];    // pad 9: spread banks
    __shared__ float hbuf[128][33];
    __shared__ float sdis[128];
    int b = blockIdx.x, t = threadIdx.x;   // 512
    int start = bbase[b], end = bbase[b + 1];
    if (t < 256) sW1[t] = W1[t];
    for (int i = t; i < 1024; i += 512) sW2[i] = W2[i];
    int base = b << SHIFT;
    if (t < 128) {
        int v = base + t;
        sdis[t] = (v < n) ? dis[v] : 0.f;
    }
    for (int i = t; i < 1024; i += 512) {
        int d = i >> 3, k = i & 7;
        int v = base + d;
        acc8[d][k] = (v < n) ? xs[(size_t)v * 8 + k] : 0.f;   // self-loop term
    }
    __syncthreads();
    int slot = t >> 1, q = t & 1;     // 256 edges/iter, 2 lanes x float4
    for (int i = start + slot; i < end; i += 256) {
        int p = bpair[i];
        int s = p >> SHIFT, d = p & BMASK;
        float4 xv = ((const float4*)xs)[(size_t)s * 2 + q];
        atomicAdd(&acc8[d][q * 4 + 0], xv.x);
        atomicAdd(&acc8[d][q * 4 + 1], xv.y);
        atomicAdd(&acc8[d][q * 4 + 2], xv.z);
        atomicAdd(&acc8[d][q * 4 + 3], xv.w);
    }
    __syncthreads();
    int f = t & 31;
    for (int d0 = t >> 5; d0 < 128; d0 += 16) {
        float a = 0.f;
#pragma unroll
        for (int j = 0; j < 8; ++j) a += acc8[d0][j] * sW1[j * 32 + f];
        hbuf[d0][f] = fmaxf(sdis[d0] * a + b1[f], 0.f);
    }
    __syncthreads();
    for (int d0 = t >> 5; d0 < 128; d0 += 16) {
        int v = base + d0;
        if (v >= n) continue;
        float a = 0.f;
#pragma unroll
        for (int k = 0; k < 32; ++k) a += hbuf[d0][k] * sW2[k * 32 + f];
        g[(size_t)v * 32 + f] = a * sdis[d0];
    }
}

// layer 2 + head: per bucket, stream edges into LDS acc (init = self g);
// out = relu(dis*acc + b2) . Wf + bf
__global__ void k_l2(const int* __restrict__ bpair, const int* __restrict__ bbase,
                     const float* __restrict__ g, const float* __restrict__ dis,
                     const float* __restrict__ b2, const float* __restrict__ Wf,
                     const float* __restrict__ bf, float* __restrict__ out, int n) {
    __shared__ float acc[128][33];    // pad 33
    __shared__ float sdis[128];
    __shared__ float sb2[32], sWf[32];
    int b = blockIdx.x, t = threadIdx.x;   // 512
    int start = bbase[b], end = bbase[b + 1];
    if (t < 32) { sb2[t] = b2[t]; sWf[t] = Wf[t]; }
    int base = b << SHIFT;
    if (t < 128) {
        int v = base + t;
        sdis[t] = (v < n) ? dis[v] : 0.f;
    }
    for (int i = t; i < 4096; i += 512) {
        int d = i >> 5, k = i & 31;
        int v = base + d;
        acc[d][k] = (v < n) ? g[(size_t)v * 32 + k] : 0.f;    // self-loop term
    }
    __syncthreads();
    int slot = t >> 3, q = t & 7;     // 64 edges/iter, 8 lanes x float4
    for (int i = start + slot; i < end; i += 64) {
        int p = bpair[i];
        int s = p >> SHIFT, d = p & BMASK;
        float4 gv = ((const float4*)g)[(size_t)s * 8 + q];
        atomicAdd(&acc[d][q * 4 + 0], gv.x);
        atomicAdd(&acc[d][q * 4 + 1], gv.y);
        atomicAdd(&acc[d][q * 4 + 2], gv.z);
        atomicAdd(&acc[d][q * 4 + 3], gv.w);
    }
    __syncthreads();
    int f = t & 15;                   // 16 lanes/node, 2 features each
    for (int d0 = t >> 4; d0 < 128; d0 += 32) {
        float dv = sdis[d0];
        float p = fmaxf(dv * acc[d0][f] + sb2[f], 0.f) * sWf[f]
                + fmaxf(dv * acc[d0][f + 16] + sb2[f + 16], 0.f) * sWf[f + 16];
#pragma unroll
        for (int m = 1; m < 16; m <<= 1) p += __shfl_xor(p, m, 64);
        int v = base + d0;
        if (f == 0 && v < n) out[v] = p + bf[0];
    }
}

extern "C" void kernel_launch(void* const* d_in, const int* in_sizes, int n_in,
                              void* d_out, int out_size, void* d_ws, size_t ws_size,
                              hipStream_t stream) {
    const float* x  = (const float*)d_in[0];
    const int*   ei = (const int*)d_in[1];   // [2, E] int32
    const float* W1 = (const float*)d_in[2];
    const float* b1 = (const float*)d_in[3];
    const float* W2 = (const float*)d_in[4];
    const float* b2 = (const float*)d_in[5];
    const float* Wf = (const float*)d_in[6];
    const float* bf = (const float*)d_in[7];
    float* out = (float*)d_out;

    const int n = in_sizes[0] / 8;
    const int E = in_sizes[1] / 2;
    const int* src = ei;
    const int* dst = ei + E;
    const int nbuck = (n + BMASK) >> SHIFT;  // n=100k -> 782 (<= 1024)

    // workspace (~25.5 MB)
    float* dis  = (float*)d_ws;                 // n
    float* xs   = dis + n;                      // 8n
    float* g    = xs + (size_t)n * 8;           // 32n
    int* part   = (int*)(g + (size_t)n * 32);   // MAXB*NBLK (16B-aligned)
    int* bbase  = part + (size_t)MAXB * NBLK;   // MAXB+1
    int* btot   = bbase + (MAXB + 1);           // MAXB
    int* bpair  = btot + MAXB;                  // E

    // --- bucket sort of edges (zero global atomics) ---
    k_hist <<<dim3(NBLK), dim3(256), 0, stream>>>(dst, part, E);
    k_scanA<<<dim3((nbuck + 3) / 4), dim3(256), 0, stream>>>(part, btot, nbuck);
    k_scanB<<<dim3(1), dim3(MAXB), 0, stream>>>(btot, bbase, nbuck, E);
    k_binA2<<<dim3(NBLK), dim3(512), 0, stream>>>(src, dst, part, bbase, bpair, E);

    // --- degree / dis / xs ---
    k_dis<<<dim3(nbuck), dim3(256), 0, stream>>>(bpair, bbase, x, dis, xs, n);

    // --- layer 1 (edge-streaming LDS accumulate + W1 + relu + W2) ---
    k_l1<<<dim3(nbuck), dim3(512), 0, stream>>>(bpair, bbase, xs, dis, W1, b1, W2, g, n);

    // --- layer 2 + head ---
    k_l2<<<dim3(nbuck), dim3(512), 0, stream>>>(bpair, bbase, g, dis, b2, Wf, bf, out, n);
}

// Round 9
// 144.455 us; speedup vs baseline: 4.0835x; 4.0835x over previous
//
#include <hip/hip_runtime.h>
#include <hip/hip_fp16.h>

// ---------------------------------------------------------------------------
// RoutingGNN: 2-layer GCN (sym-norm, self-loops) + linear head.
// Round 9: revert round-8's LDS-atomic streaming (427us, atomic-serialized).
// Back to round-7 structure; new lever: fp16 intermediates.
//   xs16 (16B/node, 1.6MB)  -> fits per-XCD L2, layer-1 gathers become L2 hits
//   g16  (64B/node, 6.4MB)  -> halves the 8-XCD-replicated layer-2 fetch
// fp32 accumulation everywhere; est. added absmax ~2e-4 vs 3.5e-3 threshold.
//   CSR build (zero global atomics): k_hist -> k_scan2 -> k_binA2 -> k_fill2
//   k_g1w2 : gather(xs16) + W1 + relu + W2(LDS) -> g16
//   k_g2f  : gather(g16) + combine + relu + Wf head -> out
// ---------------------------------------------------------------------------

#define NBLK 256
#define SHIFT 8          // 256 nodes/bucket; n <= 131072 -> <= 512 buckets
#define BMASK 255

// per-block bucket histogram -> part[b][512]  (no global atomics)
__global__ void k_hist(const int* __restrict__ dst, int* __restrict__ part, int E) {
    __shared__ int hist[512];
    int t = threadIdx.x;           // 256
    hist[t] = 0; hist[t + 256] = 0;
    __syncthreads();
    int E4 = E >> 2;
    int chunk4 = (E4 + NBLK - 1) / NBLK;
    int b = blockIdx.x;
    int s4 = b * chunk4;
    int e4 = min(s4 + chunk4, E4);
    const int4* dst4 = (const int4*)dst;
    for (int i = s4 + t; i < e4; i += 256) {
        int4 d = dst4[i];
        atomicAdd(&hist[d.x >> SHIFT], 1);
        atomicAdd(&hist[d.y >> SHIFT], 1);
        atomicAdd(&hist[d.z >> SHIFT], 1);
        atomicAdd(&hist[d.w >> SHIFT], 1);
    }
    if (b == NBLK - 1) {
        for (int e = (E4 << 2) + t; e < E; e += 256)
            atomicAdd(&hist[dst[e] >> SHIFT], 1);
    }
    __syncthreads();
    part[b * 512 + t] = hist[t];
    part[b * 512 + 256 + t] = hist[t + 256];
}

// single block, 512 thr: column-walk partials -> per-block exclusive offsets;
// LDS scan of column totals -> bbase (exclusive bucket bases)
__global__ void k_scan2(int* __restrict__ part, int* __restrict__ bbase,
                        int* __restrict__ rowptr, int n, int E) {
    __shared__ int tmp[512];
    int t = threadIdx.x;
    int run = 0;
    for (int b = 0; b < NBLK; b += 4) {
        int i0 = (b + 0) * 512 + t, i1 = (b + 1) * 512 + t;
        int i2 = (b + 2) * 512 + t, i3 = (b + 3) * 512 + t;
        int c0 = part[i0], c1 = part[i1], c2 = part[i2], c3 = part[i3];
        part[i0] = run; run += c0;
        part[i1] = run; run += c1;
        part[i2] = run; run += c2;
        part[i3] = run; run += c3;
    }
    tmp[t] = run;
    __syncthreads();
    int v = run;
    for (int off = 1; off < 512; off <<= 1) {
        int add = (t >= off) ? tmp[t - off] : 0;
        __syncthreads();
        tmp[t] += add;
        __syncthreads();
    }
    bbase[t] = tmp[t] - v;
    if (t == 511) bbase[512] = tmp[511];
    if (t == 0) rowptr[n] = E;
}

// bin edges into bucket-ordered packed words via block-private LDS cursors
__global__ void k_binA2(const int* __restrict__ src, const int* __restrict__ dst,
                        const int* __restrict__ part, const int* __restrict__ bbase,
                        int* __restrict__ bpair, int E) {
    __shared__ int cur[512];
    int t = threadIdx.x;           // 512
    int b = blockIdx.x;
    cur[t] = part[b * 512 + t] + bbase[t];
    __syncthreads();
    int E4 = E >> 2;
    int chunk4 = (E4 + NBLK - 1) / NBLK;
    int s4 = b * chunk4;
    int e4 = min(s4 + chunk4, E4);
    const int4* src4 = (const int4*)src;
    const int4* dst4 = (const int4*)dst;
    for (int i = s4 + t; i < e4; i += 512) {
        int4 s = src4[i];
        int4 d = dst4[i];
        int p0 = atomicAdd(&cur[d.x >> SHIFT], 1);
        bpair[p0] = (s.x << SHIFT) | (d.x & BMASK);
        int p1 = atomicAdd(&cur[d.y >> SHIFT], 1);
        bpair[p1] = (s.y << SHIFT) | (d.y & BMASK);
        int p2 = atomicAdd(&cur[d.z >> SHIFT], 1);
        bpair[p2] = (s.z << SHIFT) | (d.z & BMASK);
        int p3 = atomicAdd(&cur[d.w >> SHIFT], 1);
        bpair[p3] = (s.w << SHIFT) | (d.w & BMASK);
    }
    if (b == NBLK - 1) {
        for (int e = (E4 << 2) + t; e < E; e += 512) {
            int sv = src[e], dv = dst[e];
            int p = atomicAdd(&cur[dv >> SHIFT], 1);
            bpair[p] = (sv << SHIFT) | (dv & BMASK);
        }
    }
}

// one block (512 thr) per bucket: LDS counting sort -> rowptr/dis/col;
// fused xs16 = fp16(x * dis), 4 uints (8 halfs) per node
__global__ void k_fill2(const int* __restrict__ bpair, const int* __restrict__ bbase,
                        const float* __restrict__ x,
                        int* __restrict__ rowptr, float* __restrict__ dis,
                        unsigned int* __restrict__ xs16, int* __restrict__ col, int n) {
    __shared__ int cnt[256];
    __shared__ int tmp[256];
    __shared__ int cur[256];
    __shared__ float sdis[256];
    int b = blockIdx.x;
    int t = threadIdx.x;           // 512
    int start = bbase[b], end = bbase[b + 1];
    if (t < 256) cnt[t] = 0;
    __syncthreads();
    for (int i = start + t; i < end; i += 512)
        atomicAdd(&cnt[bpair[i] & BMASK], 1);
    __syncthreads();
    int v0 = (t < 256) ? cnt[t] : 0;
    if (t < 256) tmp[t] = v0;
    __syncthreads();
    for (int off = 1; off < 256; off <<= 1) {
        int add = (t < 256 && t >= off) ? tmp[t - off] : 0;
        __syncthreads();
        if (t < 256) tmp[t] += add;
        __syncthreads();
    }
    if (t < 256) {
        int v = (b << SHIFT) + t;
        if (v < n) {
            int r = start + tmp[t] - v0;
            rowptr[v] = r;
            cur[t] = r;
            float dv = rsqrtf(1.0f + (float)v0);
            dis[v] = dv;
            sdis[t] = dv;
        }
    }
    __syncthreads();
    // xs16: node row = 4 uints (8 halfs). bucket covers 256 nodes = 1024 uints
    int ubase = (b << SHIFT) * 4;
    int nu = n * 4;
    const float2* x2 = (const float2*)x;
    for (int i = t; i < 1024; i += 512) {
        int gi = ubase + i;
        if (gi < nu) {
            float d = sdis[i >> 2];
            float2 xv = x2[gi];
            __half2 h2 = __float22half2_rn(make_float2(xv.x * d, xv.y * d));
            xs16[gi] = *(unsigned int*)&h2;
        }
    }
    for (int i = start + t; i < end; i += 512) {
        int p = bpair[i];
        int pos = atomicAdd(&cur[p & BMASK], 1);
        col[pos] = p >> SHIFT;
    }
}

// layer 1 fused: agg8 = sum_{u->v} xs16[u] (+ self);
// h = relu(dis*(agg8@W1)+b1);  g16 = fp16(dis*(h@W2))
// 16 edge-slots x 4 lanes x half2; W2 matvec via LDS split-k across halves.
__global__ void k_g1w2(const int* __restrict__ rowptr, const int* __restrict__ col,
                       const __half2* __restrict__ xsh2, const float* __restrict__ dis,
                       const float* __restrict__ W1, const float* __restrict__ b1,
                       const float* __restrict__ W2, unsigned int* __restrict__ g16, int n) {
    __shared__ float sW1[256];
    __shared__ float sW2[1024];
    __shared__ float sh[4][32];
    int t = threadIdx.x;
    sW1[t] = W1[t];
    for (int i = t; i < 1024; i += 256) sW2[i] = W2[i];
    __syncthreads();
    int widx = t >> 6;
    int v = blockIdx.x * 4 + widx;
    if (v >= n) return;
    int lane = t & 63, slot = lane >> 2, q = lane & 3;
    int r0 = rowptr[v], r1 = rowptr[v + 1];
    float2 s = make_float2(0.f, 0.f);
    for (int i = r0 + slot; i < r1; i += 16) {
        float2 xf = __half22float2(xsh2[(size_t)col[i] * 4 + q]);
        s.x += xf.x; s.y += xf.y;
    }
#pragma unroll
    for (int m = 4; m < 64; m <<= 1) {
        s.x += __shfl_xor(s.x, m, 64);
        s.y += __shfl_xor(s.y, m, 64);
    }
    float2 xf = __half22float2(xsh2[(size_t)v * 4 + q]);   // self-loop
    s.x += xf.x; s.y += xf.y;
    float tq[8];
#pragma unroll
    for (int j = 0; j < 4; ++j) {
        tq[2 * j]     = __shfl(s.x, j, 64);
        tq[2 * j + 1] = __shfl(s.y, j, 64);
    }
    int f = lane & 31, half = lane >> 5;
    float dv = dis[v];
    float acc = 0.f;
#pragma unroll
    for (int j = 0; j < 8; ++j) acc += tq[j] * sW1[j * 32 + f];
    float hp = fmaxf(dv * acc + b1[f], 0.f);
    if (half == 0) sh[widx][f] = hp;
    float g2 = 0.f;
    int k0 = half << 4;
#pragma unroll
    for (int k = 0; k < 16; ++k) g2 += sh[widx][k0 + k] * sW2[(k0 + k) * 32 + f];
    g2 += __shfl_xor(g2, 32, 64);
    float val = g2 * dv;
    float other = __shfl_xor(val, 1, 64);
    if (lane < 32 && (lane & 1) == 0) {
        __half2 h2 = __float22half2_rn(make_float2(val, other));
        g16[(size_t)v * 16 + (lane >> 1)] = *(unsigned int*)&h2;
    }
}

// layer 2 + head fused: 16 edge-slots x 4 lanes, uint4 (8 halfs) per lane.
__global__ void k_g2f(const int* __restrict__ rowptr, const int* __restrict__ col,
                      const uint4* __restrict__ g16u4, const float* __restrict__ dis,
                      const float* __restrict__ b2, const float* __restrict__ Wf,
                      const float* __restrict__ bf, float* __restrict__ out, int n) {
    int t = threadIdx.x;
    int v = blockIdx.x * 4 + (t >> 6);
    if (v >= n) return;
    int lane = t & 63, slot = lane >> 2, q = lane & 3;
    int r0 = rowptr[v], r1 = rowptr[v + 1];
    float4 s0 = make_float4(0.f, 0.f, 0.f, 0.f);
    float4 s1 = make_float4(0.f, 0.f, 0.f, 0.f);
    for (int i = r0 + slot; i < r1; i += 16) {
        uint4 raw = g16u4[(size_t)col[i] * 4 + q];
        float2 f0 = __half22float2(*(const __half2*)&raw.x);
        float2 f1 = __half22float2(*(const __half2*)&raw.y);
        float2 f2 = __half22float2(*(const __half2*)&raw.z);
        float2 f3 = __half22float2(*(const __half2*)&raw.w);
        s0.x += f0.x; s0.y += f0.y; s0.z += f1.x; s0.w += f1.y;
        s1.x += f2.x; s1.y += f2.y; s1.z += f3.x; s1.w += f3.y;
    }
#pragma unroll
    for (int m = 4; m < 64; m <<= 1) {
        s0.x += __shfl_xor(s0.x, m, 64);
        s0.y += __shfl_xor(s0.y, m, 64);
        s0.z += __shfl_xor(s0.z, m, 64);
        s0.w += __shfl_xor(s0.w, m, 64);
        s1.x += __shfl_xor(s1.x, m, 64);
        s1.y += __shfl_xor(s1.y, m, 64);
        s1.z += __shfl_xor(s1.z, m, 64);
        s1.w += __shfl_xor(s1.w, m, 64);
    }
    {   // self-loop
        uint4 raw = g16u4[(size_t)v * 4 + q];
        float2 f0 = __half22float2(*(const __half2*)&raw.x);
        float2 f1 = __half22float2(*(const __half2*)&raw.y);
        float2 f2 = __half22float2(*(const __half2*)&raw.z);
        float2 f3 = __half22float2(*(const __half2*)&raw.w);
        s0.x += f0.x; s0.y += f0.y; s0.z += f1.x; s0.w += f1.y;
        s1.x += f2.x; s1.y += f2.y; s1.z += f3.x; s1.w += f3.y;
    }
    float dv = dis[v];
    float4 bv0 = ((const float4*)b2)[q * 2], bv1 = ((const float4*)b2)[q * 2 + 1];
    float4 wv0 = ((const float4*)Wf)[q * 2], wv1 = ((const float4*)Wf)[q * 2 + 1];
    float p = fmaxf(dv * s0.x + bv0.x, 0.f) * wv0.x
            + fmaxf(dv * s0.y + bv0.y, 0.f) * wv0.y
            + fmaxf(dv * s0.z + bv0.z, 0.f) * wv0.z
            + fmaxf(dv * s0.w + bv0.w, 0.f) * wv0.w
            + fmaxf(dv * s1.x + bv1.x, 0.f) * wv1.x
            + fmaxf(dv * s1.y + bv1.y, 0.f) * wv1.y
            + fmaxf(dv * s1.z + bv1.z, 0.f) * wv1.z
            + fmaxf(dv * s1.w + bv1.w, 0.f) * wv1.w;
    p += __shfl_xor(p, 1, 64);
    p += __shfl_xor(p, 2, 64);
    if (lane == 0) out[v] = p + bf[0];
}

extern "C" void kernel_launch(void* const* d_in, const int* in_sizes, int n_in,
                              void* d_out, int out_size, void* d_ws, size_t ws_size,
                              hipStream_t stream) {
    const float* x  = (const float*)d_in[0];
    const int*   ei = (const int*)d_in[1];   // [2, E] int32
    const float* W1 = (const float*)d_in[2];
    const float* b1 = (const float*)d_in[3];
    const float* W2 = (const float*)d_in[4];
    const float* b2 = (const float*)d_in[5];
    const float* Wf = (const float*)d_in[6];
    const float* bf = (const float*)d_in[7];
    float* out = (float*)d_out;

    const int n = in_sizes[0] / 8;
    const int E = in_sizes[1] / 2;
    const int* src = ei;
    const int* dst = ei + E;
    const int nbuck = (n + 255) >> 8;        // n=100k -> 391
    const size_t na = (size_t)((n + 3) & ~3);  // align fp16 arrays to 16B

    // workspace (~25 MB)
    float* dis         = (float*)d_ws;                  // n
    unsigned int* xs16 = (unsigned int*)(dis + na);     // 4n uints (8 halfs/node)
    unsigned int* g16  = xs16 + na * 4;                 // 16n uints (32 halfs/node)
    int* rowptr        = (int*)(g16 + na * 16);         // n+1
    int* bbase         = rowptr + (n + 1);              // 513
    int* part          = bbase + 513;                   // NBLK*512
    int* col           = part + NBLK * 512;             // E
    int* bpair         = col + E;                       // E

    // --- CSR build (zero global atomics) ---
    k_hist <<<dim3(NBLK), dim3(256), 0, stream>>>(dst, part, E);
    k_scan2<<<dim3(1),    dim3(512), 0, stream>>>(part, bbase, rowptr, n, E);
    k_binA2<<<dim3(NBLK), dim3(512), 0, stream>>>(src, dst, part, bbase, bpair, E);
    k_fill2<<<dim3(nbuck),dim3(512), 0, stream>>>(bpair, bbase, x, rowptr, dis, xs16, col, n);

    // --- layer 1 (gather + W1 + relu + W2, LDS-fused) -> g16 ---
    k_g1w2<<<dim3((n + 3) / 4), dim3(256), 0, stream>>>(rowptr, col, (const __half2*)xs16,
                                                        dis, W1, b1, W2, g16, n);

    // --- layer 2 + head ---
    k_g2f<<<dim3((n + 3) / 4), dim3(256), 0, stream>>>(rowptr, col, (const uint4*)g16, dis,
                                                       b2, Wf, bf, out, n);
}

// Round 10
// 117.252 us; speedup vs baseline: 5.0309x; 1.2320x over previous
//
#include <hip/hip_runtime.h>
#include <hip/hip_fp16.h>

// ---------------------------------------------------------------------------
// RoutingGNN: 2-layer GCN (sym-norm, self-loops) + linear head.
// Round 10: restructure layer 1 to 8 nodes/wave. fp16 xs row = 16B = one
// uint4, so each lane gathers WHOLE node rows; 8-lane butterfly gives every
// lane the full agg8; each lane computes 4 features of W1 and W2 (h staged
// in padded LDS [8][33], wave-internal). Per-node DS ops ~50 -> ~11.
//   CSR build (zero global atomics): k_hist -> k_scan2 -> k_binA2 -> k_fill2
//   k_g1b  : 8 nodes/wave gather(xs16) + W1 + relu + W2 -> g16
//   k_g2f  : gather(g16) + combine + relu + Wf head -> out
// ---------------------------------------------------------------------------

#define NBLK 256
#define SHIFT 8          // 256 nodes/bucket; n <= 131072 -> <= 512 buckets
#define BMASK 255

// per-block bucket histogram -> part[b][512]  (no global atomics)
__global__ void k_hist(const int* __restrict__ dst, int* __restrict__ part, int E) {
    __shared__ int hist[512];
    int t = threadIdx.x;           // 256
    hist[t] = 0; hist[t + 256] = 0;
    __syncthreads();
    int E4 = E >> 2;
    int chunk4 = (E4 + NBLK - 1) / NBLK;
    int b = blockIdx.x;
    int s4 = b * chunk4;
    int e4 = min(s4 + chunk4, E4);
    const int4* dst4 = (const int4*)dst;
    for (int i = s4 + t; i < e4; i += 256) {
        int4 d = dst4[i];
        atomicAdd(&hist[d.x >> SHIFT], 1);
        atomicAdd(&hist[d.y >> SHIFT], 1);
        atomicAdd(&hist[d.z >> SHIFT], 1);
        atomicAdd(&hist[d.w >> SHIFT], 1);
    }
    if (b == NBLK - 1) {
        for (int e = (E4 << 2) + t; e < E; e += 256)
            atomicAdd(&hist[dst[e] >> SHIFT], 1);
    }
    __syncthreads();
    part[b * 512 + t] = hist[t];
    part[b * 512 + 256 + t] = hist[t + 256];
}

// single block, 512 thr: column-walk partials -> per-block exclusive offsets;
// LDS scan of column totals -> bbase (exclusive bucket bases)
__global__ void k_scan2(int* __restrict__ part, int* __restrict__ bbase,
                        int* __restrict__ rowptr, int n, int E) {
    __shared__ int tmp[512];
    int t = threadIdx.x;
    int run = 0;
    for (int b = 0; b < NBLK; b += 4) {
        int i0 = (b + 0) * 512 + t, i1 = (b + 1) * 512 + t;
        int i2 = (b + 2) * 512 + t, i3 = (b + 3) * 512 + t;
        int c0 = part[i0], c1 = part[i1], c2 = part[i2], c3 = part[i3];
        part[i0] = run; run += c0;
        part[i1] = run; run += c1;
        part[i2] = run; run += c2;
        part[i3] = run; run += c3;
    }
    tmp[t] = run;
    __syncthreads();
    int v = run;
    for (int off = 1; off < 512; off <<= 1) {
        int add = (t >= off) ? tmp[t - off] : 0;
        __syncthreads();
        tmp[t] += add;
        __syncthreads();
    }
    bbase[t] = tmp[t] - v;
    if (t == 511) bbase[512] = tmp[511];
    if (t == 0) rowptr[n] = E;
}

// bin edges into bucket-ordered packed words via block-private LDS cursors
__global__ void k_binA2(const int* __restrict__ src, const int* __restrict__ dst,
                        const int* __restrict__ part, const int* __restrict__ bbase,
                        int* __restrict__ bpair, int E) {
    __shared__ int cur[512];
    int t = threadIdx.x;           // 512
    int b = blockIdx.x;
    cur[t] = part[b * 512 + t] + bbase[t];
    __syncthreads();
    int E4 = E >> 2;
    int chunk4 = (E4 + NBLK - 1) / NBLK;
    int s4 = b * chunk4;
    int e4 = min(s4 + chunk4, E4);
    const int4* src4 = (const int4*)src;
    const int4* dst4 = (const int4*)dst;
    for (int i = s4 + t; i < e4; i += 512) {
        int4 s = src4[i];
        int4 d = dst4[i];
        int p0 = atomicAdd(&cur[d.x >> SHIFT], 1);
        bpair[p0] = (s.x << SHIFT) | (d.x & BMASK);
        int p1 = atomicAdd(&cur[d.y >> SHIFT], 1);
        bpair[p1] = (s.y << SHIFT) | (d.y & BMASK);
        int p2 = atomicAdd(&cur[d.z >> SHIFT], 1);
        bpair[p2] = (s.z << SHIFT) | (d.z & BMASK);
        int p3 = atomicAdd(&cur[d.w >> SHIFT], 1);
        bpair[p3] = (s.w << SHIFT) | (d.w & BMASK);
    }
    if (b == NBLK - 1) {
        for (int e = (E4 << 2) + t; e < E; e += 512) {
            int sv = src[e], dv = dst[e];
            int p = atomicAdd(&cur[dv >> SHIFT], 1);
            bpair[p] = (sv << SHIFT) | (dv & BMASK);
        }
    }
}

// one block (512 thr) per bucket: LDS counting sort -> rowptr/dis/col;
// fused xs16 = fp16(x * dis), 4 uints (8 halfs) per node
__global__ void k_fill2(const int* __restrict__ bpair, const int* __restrict__ bbase,
                        const float* __restrict__ x,
                        int* __restrict__ rowptr, float* __restrict__ dis,
                        unsigned int* __restrict__ xs16, int* __restrict__ col, int n) {
    __shared__ int cnt[256];
    __shared__ int tmp[256];
    __shared__ int cur[256];
    __shared__ float sdis[256];
    int b = blockIdx.x;
    int t = threadIdx.x;           // 512
    int start = bbase[b], end = bbase[b + 1];
    if (t < 256) cnt[t] = 0;
    __syncthreads();
    for (int i = start + t; i < end; i += 512)
        atomicAdd(&cnt[bpair[i] & BMASK], 1);
    __syncthreads();
    int v0 = (t < 256) ? cnt[t] : 0;
    if (t < 256) tmp[t] = v0;
    __syncthreads();
    for (int off = 1; off < 256; off <<= 1) {
        int add = (t < 256 && t >= off) ? tmp[t - off] : 0;
        __syncthreads();
        if (t < 256) tmp[t] += add;
        __syncthreads();
    }
    if (t < 256) {
        int v = (b << SHIFT) + t;
        if (v < n) {
            int r = start + tmp[t] - v0;
            rowptr[v] = r;
            cur[t] = r;
            float dv = rsqrtf(1.0f + (float)v0);
            dis[v] = dv;
            sdis[t] = dv;
        }
    }
    __syncthreads();
    // xs16: node row = 4 uints (8 halfs). bucket covers 256 nodes = 1024 uints
    int ubase = (b << SHIFT) * 4;
    int nu = n * 4;
    const float2* x2 = (const float2*)x;
    for (int i = t; i < 1024; i += 512) {
        int gi = ubase + i;
        if (gi < nu) {
            float d = sdis[i >> 2];
            float2 xv = x2[gi];
            __half2 h2 = __float22half2_rn(make_float2(xv.x * d, xv.y * d));
            xs16[gi] = *(unsigned int*)&h2;
        }
    }
    for (int i = start + t; i < end; i += 512) {
        int p = bpair[i];
        int pos = atomicAdd(&cur[p & BMASK], 1);
        col[pos] = p >> SHIFT;
    }
}

// layer 1, 8 nodes/wave: lane group of 8 per node; each lane gathers whole
// 16B xs16 rows; butterfly -> full agg8 in every lane; lane computes 4
// features of W1 and of W2 (h via padded LDS, wave-internal).
__global__ void k_g1b(const int* __restrict__ rowptr, const int* __restrict__ col,
                      const uint4* __restrict__ xs16u4, const float* __restrict__ dis,
                      const float* __restrict__ W1, const float* __restrict__ b1,
                      const float* __restrict__ W2, uint2* __restrict__ g16u2, int n) {
    __shared__ float sW1[256];
    __shared__ float sW2[1024];
    __shared__ float sh[4][8][33];   // wave, node, feature (pad 33)
    int t = threadIdx.x;             // 256 = 4 waves
    sW1[t] = W1[t];
    for (int i = t; i < 1024; i += 256) sW2[i] = W2[i];
    __syncthreads();
    int widx = t >> 6, lane = t & 63;
    int nd = lane >> 3, j = lane & 7;
    int v = (blockIdx.x * 4 + widx) * 8 + nd;
    float a0 = 0.f, a1 = 0.f, a2 = 0.f, a3 = 0.f,
          a4 = 0.f, a5 = 0.f, a6 = 0.f, a7 = 0.f;
    int r0 = 0, r1 = 0;
    if (v < n) { r0 = rowptr[v]; r1 = rowptr[v + 1]; }
    for (int i = r0 + j; i < r1; i += 8) {
        uint4 raw = xs16u4[col[i]];
        float2 f0 = __half22float2(*(const __half2*)&raw.x);
        float2 f1 = __half22float2(*(const __half2*)&raw.y);
        float2 f2 = __half22float2(*(const __half2*)&raw.z);
        float2 f3 = __half22float2(*(const __half2*)&raw.w);
        a0 += f0.x; a1 += f0.y; a2 += f1.x; a3 += f1.y;
        a4 += f2.x; a5 += f2.y; a6 += f3.x; a7 += f3.y;
    }
    if (j == 0 && v < n) {           // self-loop
        uint4 raw = xs16u4[v];
        float2 f0 = __half22float2(*(const __half2*)&raw.x);
        float2 f1 = __half22float2(*(const __half2*)&raw.y);
        float2 f2 = __half22float2(*(const __half2*)&raw.z);
        float2 f3 = __half22float2(*(const __half2*)&raw.w);
        a0 += f0.x; a1 += f0.y; a2 += f1.x; a3 += f1.y;
        a4 += f2.x; a5 += f2.y; a6 += f3.x; a7 += f3.y;
    }
#pragma unroll
    for (int m = 1; m < 8; m <<= 1) {
        a0 += __shfl_xor(a0, m, 64);
        a1 += __shfl_xor(a1, m, 64);
        a2 += __shfl_xor(a2, m, 64);
        a3 += __shfl_xor(a3, m, 64);
        a4 += __shfl_xor(a4, m, 64);
        a5 += __shfl_xor(a5, m, 64);
        a6 += __shfl_xor(a6, m, 64);
        a7 += __shfl_xor(a7, m, 64);
    }
    float dv = (v < n) ? dis[v] : 0.f;
    int f0i = j * 4;
    float h0 = 0.f, h1 = 0.f, h2 = 0.f, h3 = 0.f;
#pragma unroll
    for (int k = 0; k < 8; ++k) {
        float ak = (k == 0) ? a0 : (k == 1) ? a1 : (k == 2) ? a2 : (k == 3) ? a3
                 : (k == 4) ? a4 : (k == 5) ? a5 : (k == 6) ? a6 : a7;
        const float* w = &sW1[k * 32 + f0i];
        h0 += ak * w[0]; h1 += ak * w[1]; h2 += ak * w[2]; h3 += ak * w[3];
    }
    h0 = fmaxf(dv * h0 + b1[f0i + 0], 0.f);
    h1 = fmaxf(dv * h1 + b1[f0i + 1], 0.f);
    h2 = fmaxf(dv * h2 + b1[f0i + 2], 0.f);
    h3 = fmaxf(dv * h3 + b1[f0i + 3], 0.f);
    sh[widx][nd][f0i + 0] = h0;
    sh[widx][nd][f0i + 1] = h1;
    sh[widx][nd][f0i + 2] = h2;
    sh[widx][nd][f0i + 3] = h3;
    // same-wave LDS RAW: DS ops are in-order per wave (round-7/9 pattern)
    float g0 = 0.f, g1 = 0.f, g2 = 0.f, g3 = 0.f;
#pragma unroll
    for (int k = 0; k < 32; ++k) {
        float hk = sh[widx][nd][k];
        const float* w = &sW2[k * 32 + f0i];
        g0 += hk * w[0]; g1 += hk * w[1]; g2 += hk * w[2]; g3 += hk * w[3];
    }
    if (v < n) {
        __half2 ha = __float22half2_rn(make_float2(g0 * dv, g1 * dv));
        __half2 hb = __float22half2_rn(make_float2(g2 * dv, g3 * dv));
        uint2 o;
        o.x = *(unsigned int*)&ha;
        o.y = *(unsigned int*)&hb;
        g16u2[(size_t)v * 8 + j] = o;
    }
}

// layer 2 + head fused: 16 edge-slots x 4 lanes, uint4 (8 halfs) per lane.
__global__ void k_g2f(const int* __restrict__ rowptr, const int* __restrict__ col,
                      const uint4* __restrict__ g16u4, const float* __restrict__ dis,
                      const float* __restrict__ b2, const float* __restrict__ Wf,
                      const float* __restrict__ bf, float* __restrict__ out, int n) {
    int t = threadIdx.x;
    int v = blockIdx.x * 4 + (t >> 6);
    if (v >= n) return;
    int lane = t & 63, slot = lane >> 2, q = lane & 3;
    int r0 = rowptr[v], r1 = rowptr[v + 1];
    float4 s0 = make_float4(0.f, 0.f, 0.f, 0.f);
    float4 s1 = make_float4(0.f, 0.f, 0.f, 0.f);
    for (int i = r0 + slot; i < r1; i += 16) {
        uint4 raw = g16u4[(size_t)col[i] * 4 + q];
        float2 f0 = __half22float2(*(const __half2*)&raw.x);
        float2 f1 = __half22float2(*(const __half2*)&raw.y);
        float2 f2 = __half22float2(*(const __half2*)&raw.z);
        float2 f3 = __half22float2(*(const __half2*)&raw.w);
        s0.x += f0.x; s0.y += f0.y; s0.z += f1.x; s0.w += f1.y;
        s1.x += f2.x; s1.y += f2.y; s1.z += f3.x; s1.w += f3.y;
    }
#pragma unroll
    for (int m = 4; m < 64; m <<= 1) {
        s0.x += __shfl_xor(s0.x, m, 64);
        s0.y += __shfl_xor(s0.y, m, 64);
        s0.z += __shfl_xor(s0.z, m, 64);
        s0.w += __shfl_xor(s0.w, m, 64);
        s1.x += __shfl_xor(s1.x, m, 64);
        s1.y += __shfl_xor(s1.y, m, 64);
        s1.z += __shfl_xor(s1.z, m, 64);
        s1.w += __shfl_xor(s1.w, m, 64);
    }
    {   // self-loop
        uint4 raw = g16u4[(size_t)v * 4 + q];
        float2 f0 = __half22float2(*(const __half2*)&raw.x);
        float2 f1 = __half22float2(*(const __half2*)&raw.y);
        float2 f2 = __half22float2(*(const __half2*)&raw.z);
        float2 f3 = __half22float2(*(const __half2*)&raw.w);
        s0.x += f0.x; s0.y += f0.y; s0.z += f1.x; s0.w += f1.y;
        s1.x += f2.x; s1.y += f2.y; s1.z += f3.x; s1.w += f3.y;
    }
    float dv = dis[v];
    float4 bv0 = ((const float4*)b2)[q * 2], bv1 = ((const float4*)b2)[q * 2 + 1];
    float4 wv0 = ((const float4*)Wf)[q * 2], wv1 = ((const float4*)Wf)[q * 2 + 1];
    float p = fmaxf(dv * s0.x + bv0.x, 0.f) * wv0.x
            + fmaxf(dv * s0.y + bv0.y, 0.f) * wv0.y
            + fmaxf(dv * s0.z + bv0.z, 0.f) * wv0.z
            + fmaxf(dv * s0.w + bv0.w, 0.f) * wv0.w
            + fmaxf(dv * s1.x + bv1.x, 0.f) * wv1.x
            + fmaxf(dv * s1.y + bv1.y, 0.f) * wv1.y
            + fmaxf(dv * s1.z + bv1.z, 0.f) * wv1.z
            + fmaxf(dv * s1.w + bv1.w, 0.f) * wv1.w;
    p += __shfl_xor(p, 1, 64);
    p += __shfl_xor(p, 2, 64);
    if (lane == 0) out[v] = p + bf[0];
}

extern "C" void kernel_launch(void* const* d_in, const int* in_sizes, int n_in,
                              void* d_out, int out_size, void* d_ws, size_t ws_size,
                              hipStream_t stream) {
    const float* x  = (const float*)d_in[0];
    const int*   ei = (const int*)d_in[1];   // [2, E] int32
    const float* W1 = (const float*)d_in[2];
    const float* b1 = (const float*)d_in[3];
    const float* W2 = (const float*)d_in[4];
    const float* b2 = (const float*)d_in[5];
    const float* Wf = (const float*)d_in[6];
    const float* bf = (const float*)d_in[7];
    float* out = (float*)d_out;

    const int n = in_sizes[0] / 8;
    const int E = in_sizes[1] / 2;
    const int* src = ei;
    const int* dst = ei + E;
    const int nbuck = (n + 255) >> 8;        // n=100k -> 391
    const size_t na = (size_t)((n + 3) & ~3);  // align fp16 arrays to 16B

    // workspace (~25 MB)
    float* dis         = (float*)d_ws;                  // n
    unsigned int* xs16 = (unsigned int*)(dis + na);     // 4n uints (8 halfs/node)
    unsigned int* g16  = xs16 + na * 4;                 // 16n uints (32 halfs/node)
    int* rowptr        = (int*)(g16 + na * 16);         // n+1
    int* bbase         = rowptr + (n + 1);              // 513
    int* part          = bbase + 513;                   // NBLK*512
    int* col           = part + NBLK * 512;             // E
    int* bpair         = col + E;                       // E

    // --- CSR build (zero global atomics) ---
    k_hist <<<dim3(NBLK), dim3(256), 0, stream>>>(dst, part, E);
    k_scan2<<<dim3(1),    dim3(512), 0, stream>>>(part, bbase, rowptr, n, E);
    k_binA2<<<dim3(NBLK), dim3(512), 0, stream>>>(src, dst, part, bbase, bpair, E);
    k_fill2<<<dim3(nbuck),dim3(512), 0, stream>>>(bpair, bbase, x, rowptr, dis, xs16, col, n);

    // --- layer 1 (8 nodes/wave, gather + W1 + relu + W2) -> g16 ---
    k_g1b<<<dim3((n + 31) / 32), dim3(256), 0, stream>>>(rowptr, col, (const uint4*)xs16,
                                                         dis, W1, b1, W2, (uint2*)g16, n);

    // --- layer 2 + head ---
    k_g2f<<<dim3((n + 3) / 4), dim3(256), 0, stream>>>(rowptr, col, (const uint4*)g16, dis,
                                                       b2, Wf, bf, out, n);
}

// Round 11
// 105.085 us; speedup vs baseline: 5.6134x; 1.1158x over previous
//
#include <hip/hip_runtime.h>
#include <hip/hip_fp16.h>

// ---------------------------------------------------------------------------
// RoutingGNN: 2-layer GCN (sym-norm, self-loops) + linear head.
// Round 11: kill the DS-pipe bottleneck. k_g2f's 4-level x 8-reg butterfly
// (32 swizzles/node, ~3.2M DS ops) -> 8 lanes/node, 8 nodes/wave, 2 edge
// slots: 10 swizzles/wave. k_g1b: batch h into regs via 8x ds_read_b128
// (36-float padded rows, bank-conflict-free) + explicit float4 weight reads.
//   CSR build (zero global atomics): k_hist -> k_scan2 -> k_binA2 -> k_fill2
//   k_g1b  : 8 nodes/wave gather(xs16) + W1 + relu + W2 -> g16
//   k_g2f  : 8 nodes/wave gather(g16) + combine + relu + Wf head -> out
// ---------------------------------------------------------------------------

#define NBLK 256
#define SHIFT 8          // 256 nodes/bucket; n <= 131072 -> <= 512 buckets
#define BMASK 255

// per-block bucket histogram -> part[b][512]  (no global atomics)
__global__ void k_hist(const int* __restrict__ dst, int* __restrict__ part, int E) {
    __shared__ int hist[512];
    int t = threadIdx.x;           // 256
    hist[t] = 0; hist[t + 256] = 0;
    __syncthreads();
    int E4 = E >> 2;
    int chunk4 = (E4 + NBLK - 1) / NBLK;
    int b = blockIdx.x;
    int s4 = b * chunk4;
    int e4 = min(s4 + chunk4, E4);
    const int4* dst4 = (const int4*)dst;
    for (int i = s4 + t; i < e4; i += 256) {
        int4 d = dst4[i];
        atomicAdd(&hist[d.x >> SHIFT], 1);
        atomicAdd(&hist[d.y >> SHIFT], 1);
        atomicAdd(&hist[d.z >> SHIFT], 1);
        atomicAdd(&hist[d.w >> SHIFT], 1);
    }
    if (b == NBLK - 1) {
        for (int e = (E4 << 2) + t; e < E; e += 256)
            atomicAdd(&hist[dst[e] >> SHIFT], 1);
    }
    __syncthreads();
    part[b * 512 + t] = hist[t];
    part[b * 512 + 256 + t] = hist[t + 256];
}

// single block, 512 thr: column-walk partials -> per-block exclusive offsets;
// LDS scan of column totals -> bbase (exclusive bucket bases)
__global__ void k_scan2(int* __restrict__ part, int* __restrict__ bbase,
                        int* __restrict__ rowptr, int n, int E) {
    __shared__ int tmp[512];
    int t = threadIdx.x;
    int run = 0;
    for (int b = 0; b < NBLK; b += 4) {
        int i0 = (b + 0) * 512 + t, i1 = (b + 1) * 512 + t;
        int i2 = (b + 2) * 512 + t, i3 = (b + 3) * 512 + t;
        int c0 = part[i0], c1 = part[i1], c2 = part[i2], c3 = part[i3];
        part[i0] = run; run += c0;
        part[i1] = run; run += c1;
        part[i2] = run; run += c2;
        part[i3] = run; run += c3;
    }
    tmp[t] = run;
    __syncthreads();
    int v = run;
    for (int off = 1; off < 512; off <<= 1) {
        int add = (t >= off) ? tmp[t - off] : 0;
        __syncthreads();
        tmp[t] += add;
        __syncthreads();
    }
    bbase[t] = tmp[t] - v;
    if (t == 511) bbase[512] = tmp[511];
    if (t == 0) rowptr[n] = E;
}

// bin edges into bucket-ordered packed words via block-private LDS cursors
__global__ void k_binA2(const int* __restrict__ src, const int* __restrict__ dst,
                        const int* __restrict__ part, const int* __restrict__ bbase,
                        int* __restrict__ bpair, int E) {
    __shared__ int cur[512];
    int t = threadIdx.x;           // 512
    int b = blockIdx.x;
    cur[t] = part[b * 512 + t] + bbase[t];
    __syncthreads();
    int E4 = E >> 2;
    int chunk4 = (E4 + NBLK - 1) / NBLK;
    int s4 = b * chunk4;
    int e4 = min(s4 + chunk4, E4);
    const int4* src4 = (const int4*)src;
    const int4* dst4 = (const int4*)dst;
    for (int i = s4 + t; i < e4; i += 512) {
        int4 s = src4[i];
        int4 d = dst4[i];
        int p0 = atomicAdd(&cur[d.x >> SHIFT], 1);
        bpair[p0] = (s.x << SHIFT) | (d.x & BMASK);
        int p1 = atomicAdd(&cur[d.y >> SHIFT], 1);
        bpair[p1] = (s.y << SHIFT) | (d.y & BMASK);
        int p2 = atomicAdd(&cur[d.z >> SHIFT], 1);
        bpair[p2] = (s.z << SHIFT) | (d.z & BMASK);
        int p3 = atomicAdd(&cur[d.w >> SHIFT], 1);
        bpair[p3] = (s.w << SHIFT) | (d.w & BMASK);
    }
    if (b == NBLK - 1) {
        for (int e = (E4 << 2) + t; e < E; e += 512) {
            int sv = src[e], dv = dst[e];
            int p = atomicAdd(&cur[dv >> SHIFT], 1);
            bpair[p] = (sv << SHIFT) | (dv & BMASK);
        }
    }
}

// one block (512 thr) per bucket: LDS counting sort -> rowptr/dis/col;
// fused xs16 = fp16(x * dis), 4 uints (8 halfs) per node
__global__ void k_fill2(const int* __restrict__ bpair, const int* __restrict__ bbase,
                        const float* __restrict__ x,
                        int* __restrict__ rowptr, float* __restrict__ dis,
                        unsigned int* __restrict__ xs16, int* __restrict__ col, int n) {
    __shared__ int cnt[256];
    __shared__ int tmp[256];
    __shared__ int cur[256];
    __shared__ float sdis[256];
    int b = blockIdx.x;
    int t = threadIdx.x;           // 512
    int start = bbase[b], end = bbase[b + 1];
    if (t < 256) cnt[t] = 0;
    __syncthreads();
    for (int i = start + t; i < end; i += 512)
        atomicAdd(&cnt[bpair[i] & BMASK], 1);
    __syncthreads();
    int v0 = (t < 256) ? cnt[t] : 0;
    if (t < 256) tmp[t] = v0;
    __syncthreads();
    for (int off = 1; off < 256; off <<= 1) {
        int add = (t < 256 && t >= off) ? tmp[t - off] : 0;
        __syncthreads();
        if (t < 256) tmp[t] += add;
        __syncthreads();
    }
    if (t < 256) {
        int v = (b << SHIFT) + t;
        if (v < n) {
            int r = start + tmp[t] - v0;
            rowptr[v] = r;
            cur[t] = r;
            float dv = rsqrtf(1.0f + (float)v0);
            dis[v] = dv;
            sdis[t] = dv;
        }
    }
    __syncthreads();
    // xs16: node row = 4 uints (8 halfs). bucket covers 256 nodes = 1024 uints
    int ubase = (b << SHIFT) * 4;
    int nu = n * 4;
    const float2* x2 = (const float2*)x;
    for (int i = t; i < 1024; i += 512) {
        int gi = ubase + i;
        if (gi < nu) {
            float d = sdis[i >> 2];
            float2 xv = x2[gi];
            __half2 h2 = __float22half2_rn(make_float2(xv.x * d, xv.y * d));
            xs16[gi] = *(unsigned int*)&h2;
        }
    }
    for (int i = start + t; i < end; i += 512) {
        int p = bpair[i];
        int pos = atomicAdd(&cur[p & BMASK], 1);
        col[pos] = p >> SHIFT;
    }
}

// layer 1, 8 nodes/wave: lane group of 8 per node; each lane gathers whole
// 16B xs16 rows; butterfly -> full agg8 in every lane; lane computes 4
// features of W1 and of W2 (h batched into regs via ds_read_b128).
__global__ void k_g1b(const int* __restrict__ rowptr, const int* __restrict__ col,
                      const uint4* __restrict__ xs16u4, const float* __restrict__ dis,
                      const float* __restrict__ W1, const float* __restrict__ b1,
                      const float* __restrict__ W2, uint2* __restrict__ g16u2, int n) {
    __shared__ float sW1[256];
    __shared__ float sW2[1024];
    __shared__ float sh[4][8][36];   // wave, node, feature (pad 36: 16B-aligned, 4-bank step)
    int t = threadIdx.x;             // 256 = 4 waves
    sW1[t] = W1[t];
    for (int i = t; i < 1024; i += 256) sW2[i] = W2[i];
    __syncthreads();
    int widx = t >> 6, lane = t & 63;
    int nd = lane >> 3, j = lane & 7;
    int v = (blockIdx.x * 4 + widx) * 8 + nd;
    float a0 = 0.f, a1 = 0.f, a2 = 0.f, a3 = 0.f,
          a4 = 0.f, a5 = 0.f, a6 = 0.f, a7 = 0.f;
    int r0 = 0, r1 = 0;
    if (v < n) { r0 = rowptr[v]; r1 = rowptr[v + 1]; }
    for (int i = r0 + j; i < r1; i += 8) {
        uint4 raw = xs16u4[col[i]];
        float2 f0 = __half22float2(*(const __half2*)&raw.x);
        float2 f1 = __half22float2(*(const __half2*)&raw.y);
        float2 f2 = __half22float2(*(const __half2*)&raw.z);
        float2 f3 = __half22float2(*(const __half2*)&raw.w);
        a0 += f0.x; a1 += f0.y; a2 += f1.x; a3 += f1.y;
        a4 += f2.x; a5 += f2.y; a6 += f3.x; a7 += f3.y;
    }
    if (j == 0 && v < n) {           // self-loop
        uint4 raw = xs16u4[v];
        float2 f0 = __half22float2(*(const __half2*)&raw.x);
        float2 f1 = __half22float2(*(const __half2*)&raw.y);
        float2 f2 = __half22float2(*(const __half2*)&raw.z);
        float2 f3 = __half22float2(*(const __half2*)&raw.w);
        a0 += f0.x; a1 += f0.y; a2 += f1.x; a3 += f1.y;
        a4 += f2.x; a5 += f2.y; a6 += f3.x; a7 += f3.y;
    }
#pragma unroll
    for (int m = 1; m < 8; m <<= 1) {
        a0 += __shfl_xor(a0, m, 64);
        a1 += __shfl_xor(a1, m, 64);
        a2 += __shfl_xor(a2, m, 64);
        a3 += __shfl_xor(a3, m, 64);
        a4 += __shfl_xor(a4, m, 64);
        a5 += __shfl_xor(a5, m, 64);
        a6 += __shfl_xor(a6, m, 64);
        a7 += __shfl_xor(a7, m, 64);
    }
    float dv = (v < n) ? dis[v] : 0.f;
    int f0i = j * 4;
    float h0 = 0.f, h1 = 0.f, h2 = 0.f, h3 = 0.f;
    {
        float ak[8] = {a0, a1, a2, a3, a4, a5, a6, a7};
#pragma unroll
        for (int k = 0; k < 8; ++k) {
            float4 w = *(const float4*)&sW1[k * 32 + f0i];
            h0 += ak[k] * w.x; h1 += ak[k] * w.y;
            h2 += ak[k] * w.z; h3 += ak[k] * w.w;
        }
    }
    h0 = fmaxf(dv * h0 + b1[f0i + 0], 0.f);
    h1 = fmaxf(dv * h1 + b1[f0i + 1], 0.f);
    h2 = fmaxf(dv * h2 + b1[f0i + 2], 0.f);
    h3 = fmaxf(dv * h3 + b1[f0i + 3], 0.f);
    *(float4*)&sh[widx][nd][f0i] = make_float4(h0, h1, h2, h3);
    // same-wave LDS RAW: DS ops are in-order per wave (round-7/9/10 pattern)
    const float4* hrow = (const float4*)&sh[widx][nd][0];
    float4 hr[8];
#pragma unroll
    for (int k4 = 0; k4 < 8; ++k4) hr[k4] = hrow[k4];
    float g0 = 0.f, g1 = 0.f, g2 = 0.f, g3 = 0.f;
#pragma unroll
    for (int k4 = 0; k4 < 8; ++k4) {
        float hk[4] = {hr[k4].x, hr[k4].y, hr[k4].z, hr[k4].w};
#pragma unroll
        for (int m = 0; m < 4; ++m) {
            float4 w = *(const float4*)&sW2[(k4 * 4 + m) * 32 + f0i];
            g0 += hk[m] * w.x; g1 += hk[m] * w.y;
            g2 += hk[m] * w.z; g3 += hk[m] * w.w;
        }
    }
    if (v < n) {
        __half2 ha = __float22half2_rn(make_float2(g0 * dv, g1 * dv));
        __half2 hb = __float22half2_rn(make_float2(g2 * dv, g3 * dv));
        uint2 o;
        o.x = *(unsigned int*)&ha;
        o.y = *(unsigned int*)&hb;
        g16u2[(size_t)v * 8 + j] = o;
    }
}

// layer 2 + head: 8 lanes/node (2 edge-slots x 4 quarters), 8 nodes/wave.
// Reduction = 8 swizzles (slot) + 2 (head scalar) instead of 32-swizzle
// butterfly per node.
__global__ void k_g2f(const int* __restrict__ rowptr, const int* __restrict__ col,
                      const uint4* __restrict__ g16u4, const float* __restrict__ dis,
                      const float* __restrict__ b2, const float* __restrict__ Wf,
                      const float* __restrict__ bf, float* __restrict__ out, int n) {
    int t = threadIdx.x;
    int wave = t >> 6, lane = t & 63;
    int nd = lane >> 3, sub = lane & 7;
    int slot = sub >> 2, q = sub & 3;
    int v = (blockIdx.x * 4 + wave) * 8 + nd;
    if (v >= n) return;              // whole 8-lane group exits together
    int r0 = rowptr[v], r1 = rowptr[v + 1];
    float4 s0 = make_float4(0.f, 0.f, 0.f, 0.f);
    float4 s1 = make_float4(0.f, 0.f, 0.f, 0.f);
    if (slot == 0) {                 // self-loop
        uint4 raw = g16u4[(size_t)v * 4 + q];
        float2 f0 = __half22float2(*(const __half2*)&raw.x);
        float2 f1 = __half22float2(*(const __half2*)&raw.y);
        float2 f2 = __half22float2(*(const __half2*)&raw.z);
        float2 f3 = __half22float2(*(const __half2*)&raw.w);
        s0.x += f0.x; s0.y += f0.y; s0.z += f1.x; s0.w += f1.y;
        s1.x += f2.x; s1.y += f2.y; s1.z += f3.x; s1.w += f3.y;
    }
    for (int i = r0 + slot; i < r1; i += 2) {
        uint4 raw = g16u4[(size_t)col[i] * 4 + q];
        float2 f0 = __half22float2(*(const __half2*)&raw.x);
        float2 f1 = __half22float2(*(const __half2*)&raw.y);
        float2 f2 = __half22float2(*(const __half2*)&raw.z);
        float2 f3 = __half22float2(*(const __half2*)&raw.w);
        s0.x += f0.x; s0.y += f0.y; s0.z += f1.x; s0.w += f1.y;
        s1.x += f2.x; s1.y += f2.y; s1.z += f3.x; s1.w += f3.y;
    }
    // slot reduce (lanes sub and sub^4)
    s0.x += __shfl_xor(s0.x, 4, 64);
    s0.y += __shfl_xor(s0.y, 4, 64);
    s0.z += __shfl_xor(s0.z, 4, 64);
    s0.w += __shfl_xor(s0.w, 4, 64);
    s1.x += __shfl_xor(s1.x, 4, 64);
    s1.y += __shfl_xor(s1.y, 4, 64);
    s1.z += __shfl_xor(s1.z, 4, 64);
    s1.w += __shfl_xor(s1.w, 4, 64);
    float dv = dis[v];
    float4 bv0 = ((const float4*)b2)[q * 2], bv1 = ((const float4*)b2)[q * 2 + 1];
    float4 wv0 = ((const float4*)Wf)[q * 2], wv1 = ((const float4*)Wf)[q * 2 + 1];
    float p = fmaxf(dv * s0.x + bv0.x, 0.f) * wv0.x
            + fmaxf(dv * s0.y + bv0.y, 0.f) * wv0.y
            + fmaxf(dv * s0.z + bv0.z, 0.f) * wv0.z
            + fmaxf(dv * s0.w + bv0.w, 0.f) * wv0.w
            + fmaxf(dv * s1.x + bv1.x, 0.f) * wv1.x
            + fmaxf(dv * s1.y + bv1.y, 0.f) * wv1.y
            + fmaxf(dv * s1.z + bv1.z, 0.f) * wv1.z
            + fmaxf(dv * s1.w + bv1.w, 0.f) * wv1.w;
    p += __shfl_xor(p, 1, 64);
    p += __shfl_xor(p, 2, 64);
    if (sub == 0) out[v] = p + bf[0];
}

extern "C" void kernel_launch(void* const* d_in, const int* in_sizes, int n_in,
                              void* d_out, int out_size, void* d_ws, size_t ws_size,
                              hipStream_t stream) {
    const float* x  = (const float*)d_in[0];
    const int*   ei = (const int*)d_in[1];   // [2, E] int32
    const float* W1 = (const float*)d_in[2];
    const float* b1 = (const float*)d_in[3];
    const float* W2 = (const float*)d_in[4];
    const float* b2 = (const float*)d_in[5];
    const float* Wf = (const float*)d_in[6];
    const float* bf = (const float*)d_in[7];
    float* out = (float*)d_out;

    const int n = in_sizes[0] / 8;
    const int E = in_sizes[1] / 2;
    const int* src = ei;
    const int* dst = ei + E;
    const int nbuck = (n + 255) >> 8;        // n=100k -> 391
    const size_t na = (size_t)((n + 3) & ~3);  // align fp16 arrays to 16B

    // workspace (~25 MB)
    float* dis         = (float*)d_ws;                  // n
    unsigned int* xs16 = (unsigned int*)(dis + na);     // 4n uints (8 halfs/node)
    unsigned int* g16  = xs16 + na * 4;                 // 16n uints (32 halfs/node)
    int* rowptr        = (int*)(g16 + na * 16);         // n+1
    int* bbase         = rowptr + (n + 1);              // 513
    int* part          = bbase + 513;                   // NBLK*512
    int* col           = part + NBLK * 512;             // E
    int* bpair         = col + E;                       // E

    // --- CSR build (zero global atomics) ---
    k_hist <<<dim3(NBLK), dim3(256), 0, stream>>>(dst, part, E);
    k_scan2<<<dim3(1),    dim3(512), 0, stream>>>(part, bbase, rowptr, n, E);
    k_binA2<<<dim3(NBLK), dim3(512), 0, stream>>>(src, dst, part, bbase, bpair, E);
    k_fill2<<<dim3(nbuck),dim3(512), 0, stream>>>(bpair, bbase, x, rowptr, dis, xs16, col, n);

    // --- layer 1 (8 nodes/wave, gather + W1 + relu + W2) -> g16 ---
    k_g1b<<<dim3((n + 31) / 32), dim3(256), 0, stream>>>(rowptr, col, (const uint4*)xs16,
                                                         dis, W1, b1, W2, (uint2*)g16, n);

    // --- layer 2 + head (8 nodes/wave, 2 edge slots) ---
    k_g2f<<<dim3((n + 31) / 32), dim3(256), 0, stream>>>(rowptr, col, (const uint4*)g16, dis,
                                                         b2, Wf, bf, out, n);
}

// Round 12
// 95.024 us; speedup vs baseline: 6.2078x; 1.1059x over previous
//
#include <hip/hip_runtime.h>
#include <hip/hip_fp16.h>

// ---------------------------------------------------------------------------
// RoutingGNN: 2-layer GCN (sym-norm, self-loops) + linear head.
// Round 12: kill k_scan2's single-block serialization (1 CU busy, 255 idle).
// Transposed partials (round-8 proven): k_hist writes part_T[bucket][blk];
// k_scanA scans each bucket row with one wave (int4 + shfl_up, 128 blocks);
// k_scanB scans the 512 bucket totals in one tiny block. binA2 reads its
// cursor column from part_T. Layers (fp16 intermediates, 8 nodes/wave)
// unchanged from round 11.
//   k_hist -> k_scanA -> k_scanB -> k_binA2 -> k_fill2   (CSR, 0 glob atomics)
//   k_g1b  : 8 nodes/wave gather(xs16) + W1 + relu + W2 -> g16
//   k_g2f  : 8 nodes/wave gather(g16) + combine + relu + Wf head -> out
// ---------------------------------------------------------------------------

#define NBLK 256
#define SHIFT 8          // 256 nodes/bucket; n <= 131072 -> <= 512 buckets
#define BMASK 255
#define NBUCK 512        // padded bucket count

// per-block bucket histogram -> part_T[bucket*NBLK + blk]  (no global atomics)
__global__ void k_hist(const int* __restrict__ dst, int* __restrict__ part, int E) {
    __shared__ int hist[NBUCK];
    int t = threadIdx.x;           // 256
    hist[t] = 0; hist[t + 256] = 0;
    __syncthreads();
    int E4 = E >> 2;
    int chunk4 = (E4 + NBLK - 1) / NBLK;
    int b = blockIdx.x;
    int s4 = b * chunk4;
    int e4 = min(s4 + chunk4, E4);
    const int4* dst4 = (const int4*)dst;
    for (int i = s4 + t; i < e4; i += 256) {
        int4 d = dst4[i];
        atomicAdd(&hist[d.x >> SHIFT], 1);
        atomicAdd(&hist[d.y >> SHIFT], 1);
        atomicAdd(&hist[d.z >> SHIFT], 1);
        atomicAdd(&hist[d.w >> SHIFT], 1);
    }
    if (b == NBLK - 1) {
        for (int e = (E4 << 2) + t; e < E; e += 256)
            atomicAdd(&hist[dst[e] >> SHIFT], 1);
    }
    __syncthreads();
    part[(size_t)t * NBLK + b] = hist[t];
    part[(size_t)(t + 256) * NBLK + b] = hist[t + 256];
}

// one wave per bucket: exclusive scan of its 256 partials (contiguous row);
// bucket total -> btot
__global__ void k_scanA(int* __restrict__ part, int* __restrict__ btot) {
    int t = threadIdx.x;           // 256 = 4 waves
    int b = blockIdx.x * 4 + (t >> 6);   // grid covers all NBUCK buckets
    int lane = t & 63;
    int4* p4 = (int4*)(part + (size_t)b * NBLK);
    int4 v = p4[lane];
    int ls = v.x + v.y + v.z + v.w;
    int s = ls;
#pragma unroll
    for (int off = 1; off < 64; off <<= 1) {
        int u = __shfl_up(s, off, 64);
        if (lane >= off) s += u;
    }
    int base = s - ls;             // exclusive
    int4 o;
    o.x = base;
    o.y = base + v.x;
    o.z = o.y + v.y;
    o.w = o.z + v.z;
    p4[lane] = o;
    if (lane == 63) btot[b] = s;
}

// single block, 512 thr: exclusive scan of bucket totals -> bbase
__global__ void k_scanB(const int* __restrict__ btot, int* __restrict__ bbase,
                        int* __restrict__ rowptr, int n, int E) {
    __shared__ int tmp[NBUCK];
    int t = threadIdx.x;
    int v = btot[t];
    tmp[t] = v;
    __syncthreads();
    for (int off = 1; off < NBUCK; off <<= 1) {
        int add = (t >= off) ? tmp[t - off] : 0;
        __syncthreads();
        tmp[t] += add;
        __syncthreads();
    }
    bbase[t] = tmp[t] - v;
    if (t == NBUCK - 1) bbase[NBUCK] = tmp[NBUCK - 1];
    if (t == 0) rowptr[n] = E;
}

// bin edges into bucket-ordered packed words via block-private LDS cursors
__global__ void k_binA2(const int* __restrict__ src, const int* __restrict__ dst,
                        const int* __restrict__ part, const int* __restrict__ bbase,
                        int* __restrict__ bpair, int E) {
    __shared__ int cur[NBUCK];
    int t = threadIdx.x;           // 512
    int b = blockIdx.x;
    cur[t] = part[(size_t)t * NBLK + b] + bbase[t];
    __syncthreads();
    int E4 = E >> 2;
    int chunk4 = (E4 + NBLK - 1) / NBLK;
    int s4 = b * chunk4;
    int e4 = min(s4 + chunk4, E4);
    const int4* src4 = (const int4*)src;
    const int4* dst4 = (const int4*)dst;
    for (int i = s4 + t; i < e4; i += 512) {
        int4 s = src4[i];
        int4 d = dst4[i];
        int p0 = atomicAdd(&cur[d.x >> SHIFT], 1);
        bpair[p0] = (s.x << SHIFT) | (d.x & BMASK);
        int p1 = atomicAdd(&cur[d.y >> SHIFT], 1);
        bpair[p1] = (s.y << SHIFT) | (d.y & BMASK);
        int p2 = atomicAdd(&cur[d.z >> SHIFT], 1);
        bpair[p2] = (s.z << SHIFT) | (d.z & BMASK);
        int p3 = atomicAdd(&cur[d.w >> SHIFT], 1);
        bpair[p3] = (s.w << SHIFT) | (d.w & BMASK);
    }
    if (b == NBLK - 1) {
        for (int e = (E4 << 2) + t; e < E; e += 512) {
            int sv = src[e], dv = dst[e];
            int p = atomicAdd(&cur[dv >> SHIFT], 1);
            bpair[p] = (sv << SHIFT) | (dv & BMASK);
        }
    }
}

// one block (512 thr) per bucket: LDS counting sort -> rowptr/dis/col;
// fused xs16 = fp16(x * dis), 4 uints (8 halfs) per node
__global__ void k_fill2(const int* __restrict__ bpair, const int* __restrict__ bbase,
                        const float* __restrict__ x,
                        int* __restrict__ rowptr, float* __restrict__ dis,
                        unsigned int* __restrict__ xs16, int* __restrict__ col, int n) {
    __shared__ int cnt[256];
    __shared__ int tmp[256];
    __shared__ int cur[256];
    __shared__ float sdis[256];
    int b = blockIdx.x;
    int t = threadIdx.x;           // 512
    int start = bbase[b], end = bbase[b + 1];
    if (t < 256) cnt[t] = 0;
    __syncthreads();
    for (int i = start + t; i < end; i += 512)
        atomicAdd(&cnt[bpair[i] & BMASK], 1);
    __syncthreads();
    int v0 = (t < 256) ? cnt[t] : 0;
    if (t < 256) tmp[t] = v0;
    __syncthreads();
    for (int off = 1; off < 256; off <<= 1) {
        int add = (t < 256 && t >= off) ? tmp[t - off] : 0;
        __syncthreads();
        if (t < 256) tmp[t] += add;
        __syncthreads();
    }
    if (t < 256) {
        int v = (b << SHIFT) + t;
        if (v < n) {
            int r = start + tmp[t] - v0;
            rowptr[v] = r;
            cur[t] = r;
            float dv = rsqrtf(1.0f + (float)v0);
            dis[v] = dv;
            sdis[t] = dv;
        }
    }
    __syncthreads();
    // xs16: node row = 4 uints (8 halfs). bucket covers 256 nodes = 1024 uints
    int ubase = (b << SHIFT) * 4;
    int nu = n * 4;
    const float2* x2 = (const float2*)x;
    for (int i = t; i < 1024; i += 512) {
        int gi = ubase + i;
        if (gi < nu) {
            float d = sdis[i >> 2];
            float2 xv = x2[gi];
            __half2 h2 = __float22half2_rn(make_float2(xv.x * d, xv.y * d));
            xs16[gi] = *(unsigned int*)&h2;
        }
    }
    for (int i = start + t; i < end; i += 512) {
        int p = bpair[i];
        int pos = atomicAdd(&cur[p & BMASK], 1);
        col[pos] = p >> SHIFT;
    }
}

// layer 1, 8 nodes/wave: lane group of 8 per node; each lane gathers whole
// 16B xs16 rows; butterfly -> full agg8 in every lane; lane computes 4
// features of W1 and of W2 (h batched into regs via ds_read_b128).
__global__ void k_g1b(const int* __restrict__ rowptr, const int* __restrict__ col,
                      const uint4* __restrict__ xs16u4, const float* __restrict__ dis,
                      const float* __restrict__ W1, const float* __restrict__ b1,
                      const float* __restrict__ W2, uint2* __restrict__ g16u2, int n) {
    __shared__ float sW1[256];
    __shared__ float sW2[1024];
    __shared__ float sh[4][8][36];   // wave, node, feature (pad 36)
    int t = threadIdx.x;             // 256 = 4 waves
    sW1[t] = W1[t];
    for (int i = t; i < 1024; i += 256) sW2[i] = W2[i];
    __syncthreads();
    int widx = t >> 6, lane = t & 63;
    int nd = lane >> 3, j = lane & 7;
    int v = (blockIdx.x * 4 + widx) * 8 + nd;
    float a0 = 0.f, a1 = 0.f, a2 = 0.f, a3 = 0.f,
          a4 = 0.f, a5 = 0.f, a6 = 0.f, a7 = 0.f;
    int r0 = 0, r1 = 0;
    if (v < n) { r0 = rowptr[v]; r1 = rowptr[v + 1]; }
    for (int i = r0 + j; i < r1; i += 8) {
        uint4 raw = xs16u4[col[i]];
        float2 f0 = __half22float2(*(const __half2*)&raw.x);
        float2 f1 = __half22float2(*(const __half2*)&raw.y);
        float2 f2 = __half22float2(*(const __half2*)&raw.z);
        float2 f3 = __half22float2(*(const __half2*)&raw.w);
        a0 += f0.x; a1 += f0.y; a2 += f1.x; a3 += f1.y;
        a4 += f2.x; a5 += f2.y; a6 += f3.x; a7 += f3.y;
    }
    if (j == 0 && v < n) {           // self-loop
        uint4 raw = xs16u4[v];
        float2 f0 = __half22float2(*(const __half2*)&raw.x);
        float2 f1 = __half22float2(*(const __half2*)&raw.y);
        float2 f2 = __half22float2(*(const __half2*)&raw.z);
        float2 f3 = __half22float2(*(const __half2*)&raw.w);
        a0 += f0.x; a1 += f0.y; a2 += f1.x; a3 += f1.y;
        a4 += f2.x; a5 += f2.y; a6 += f3.x; a7 += f3.y;
    }
#pragma unroll
    for (int m = 1; m < 8; m <<= 1) {
        a0 += __shfl_xor(a0, m, 64);
        a1 += __shfl_xor(a1, m, 64);
        a2 += __shfl_xor(a2, m, 64);
        a3 += __shfl_xor(a3, m, 64);
        a4 += __shfl_xor(a4, m, 64);
        a5 += __shfl_xor(a5, m, 64);
        a6 += __shfl_xor(a6, m, 64);
        a7 += __shfl_xor(a7, m, 64);
    }
    float dv = (v < n) ? dis[v] : 0.f;
    int f0i = j * 4;
    float h0 = 0.f, h1 = 0.f, h2 = 0.f, h3 = 0.f;
    {
        float ak[8] = {a0, a1, a2, a3, a4, a5, a6, a7};
#pragma unroll
        for (int k = 0; k < 8; ++k) {
            float4 w = *(const float4*)&sW1[k * 32 + f0i];
            h0 += ak[k] * w.x; h1 += ak[k] * w.y;
            h2 += ak[k] * w.z; h3 += ak[k] * w.w;
        }
    }
    h0 = fmaxf(dv * h0 + b1[f0i + 0], 0.f);
    h1 = fmaxf(dv * h1 + b1[f0i + 1], 0.f);
    h2 = fmaxf(dv * h2 + b1[f0i + 2], 0.f);
    h3 = fmaxf(dv * h3 + b1[f0i + 3], 0.f);
    *(float4*)&sh[widx][nd][f0i] = make_float4(h0, h1, h2, h3);
    // same-wave LDS RAW: DS ops are in-order per wave
    const float4* hrow = (const float4*)&sh[widx][nd][0];
    float4 hr[8];
#pragma unroll
    for (int k4 = 0; k4 < 8; ++k4) hr[k4] = hrow[k4];
    float g0 = 0.f, g1 = 0.f, g2 = 0.f, g3 = 0.f;
#pragma unroll
    for (int k4 = 0; k4 < 8; ++k4) {
        float hk[4] = {hr[k4].x, hr[k4].y, hr[k4].z, hr[k4].w};
#pragma unroll
        for (int m = 0; m < 4; ++m) {
            float4 w = *(const float4*)&sW2[(k4 * 4 + m) * 32 + f0i];
            g0 += hk[m] * w.x; g1 += hk[m] * w.y;
            g2 += hk[m] * w.z; g3 += hk[m] * w.w;
        }
    }
    if (v < n) {
        __half2 ha = __float22half2_rn(make_float2(g0 * dv, g1 * dv));
        __half2 hb = __float22half2_rn(make_float2(g2 * dv, g3 * dv));
        uint2 o;
        o.x = *(unsigned int*)&ha;
        o.y = *(unsigned int*)&hb;
        g16u2[(size_t)v * 8 + j] = o;
    }
}

// layer 2 + head: 8 lanes/node (2 edge-slots x 4 quarters), 8 nodes/wave.
__global__ void k_g2f(const int* __restrict__ rowptr, const int* __restrict__ col,
                      const uint4* __restrict__ g16u4, const float* __restrict__ dis,
                      const float* __restrict__ b2, const float* __restrict__ Wf,
                      const float* __restrict__ bf, float* __restrict__ out, int n) {
    int t = threadIdx.x;
    int wave = t >> 6, lane = t & 63;
    int nd = lane >> 3, sub = lane & 7;
    int slot = sub >> 2, q = sub & 3;
    int v = (blockIdx.x * 4 + wave) * 8 + nd;
    if (v >= n) return;              // whole 8-lane group exits together
    int r0 = rowptr[v], r1 = rowptr[v + 1];
    float4 s0 = make_float4(0.f, 0.f, 0.f, 0.f);
    float4 s1 = make_float4(0.f, 0.f, 0.f, 0.f);
    if (slot == 0) {                 // self-loop
        uint4 raw = g16u4[(size_t)v * 4 + q];
        float2 f0 = __half22float2(*(const __half2*)&raw.x);
        float2 f1 = __half22float2(*(const __half2*)&raw.y);
        float2 f2 = __half22float2(*(const __half2*)&raw.z);
        float2 f3 = __half22float2(*(const __half2*)&raw.w);
        s0.x += f0.x; s0.y += f0.y; s0.z += f1.x; s0.w += f1.y;
        s1.x += f2.x; s1.y += f2.y; s1.z += f3.x; s1.w += f3.y;
    }
    for (int i = r0 + slot; i < r1; i += 2) {
        uint4 raw = g16u4[(size_t)col[i] * 4 + q];
        float2 f0 = __half22float2(*(const __half2*)&raw.x);
        float2 f1 = __half22float2(*(const __half2*)&raw.y);
        float2 f2 = __half22float2(*(const __half2*)&raw.z);
        float2 f3 = __half22float2(*(const __half2*)&raw.w);
        s0.x += f0.x; s0.y += f0.y; s0.z += f1.x; s0.w += f1.y;
        s1.x += f2.x; s1.y += f2.y; s1.z += f3.x; s1.w += f3.y;
    }
    // slot reduce (lanes sub and sub^4)
    s0.x += __shfl_xor(s0.x, 4, 64);
    s0.y += __shfl_xor(s0.y, 4, 64);
    s0.z += __shfl_xor(s0.z, 4, 64);
    s0.w += __shfl_xor(s0.w, 4, 64);
    s1.x += __shfl_xor(s1.x, 4, 64);
    s1.y += __shfl_xor(s1.y, 4, 64);
    s1.z += __shfl_xor(s1.z, 4, 64);
    s1.w += __shfl_xor(s1.w, 4, 64);
    float dv = dis[v];
    float4 bv0 = ((const float4*)b2)[q * 2], bv1 = ((const float4*)b2)[q * 2 + 1];
    float4 wv0 = ((const float4*)Wf)[q * 2], wv1 = ((const float4*)Wf)[q * 2 + 1];
    float p = fmaxf(dv * s0.x + bv0.x, 0.f) * wv0.x
            + fmaxf(dv * s0.y + bv0.y, 0.f) * wv0.y
            + fmaxf(dv * s0.z + bv0.z, 0.f) * wv0.z
            + fmaxf(dv * s0.w + bv0.w, 0.f) * wv0.w
            + fmaxf(dv * s1.x + bv1.x, 0.f) * wv1.x
            + fmaxf(dv * s1.y + bv1.y, 0.f) * wv1.y
            + fmaxf(dv * s1.z + bv1.z, 0.f) * wv1.z
            + fmaxf(dv * s1.w + bv1.w, 0.f) * wv1.w;
    p += __shfl_xor(p, 1, 64);
    p += __shfl_xor(p, 2, 64);
    if (sub == 0) out[v] = p + bf[0];
}

extern "C" void kernel_launch(void* const* d_in, const int* in_sizes, int n_in,
                              void* d_out, int out_size, void* d_ws, size_t ws_size,
                              hipStream_t stream) {
    const float* x  = (const float*)d_in[0];
    const int*   ei = (const int*)d_in[1];   // [2, E] int32
    const float* W1 = (const float*)d_in[2];
    const float* b1 = (const float*)d_in[3];
    const float* W2 = (const float*)d_in[4];
    const float* b2 = (const float*)d_in[5];
    const float* Wf = (const float*)d_in[6];
    const float* bf = (const float*)d_in[7];
    float* out = (float*)d_out;

    const int n = in_sizes[0] / 8;
    const int E = in_sizes[1] / 2;
    const int* src = ei;
    const int* dst = ei + E;
    const int nbuck = (n + 255) >> 8;        // n=100k -> 391 (active buckets)
    const size_t na = (size_t)((n + 3) & ~3);  // align fp16 arrays to 16B

    // workspace (~25 MB)
    float* dis         = (float*)d_ws;                  // n
    unsigned int* xs16 = (unsigned int*)(dis + na);     // 4n uints (8 halfs/node)
    unsigned int* g16  = xs16 + na * 4;                 // 16n uints (32 halfs/node)
    int* rowptr        = (int*)(g16 + na * 16);         // n+1
    int* bbase         = rowptr + (n + 1);              // NBUCK+1
    int* btot          = bbase + (NBUCK + 1);           // NBUCK
    int* part          = btot + NBUCK + 2;              // NBUCK*NBLK (align 16B)
    int* col           = part + (size_t)NBUCK * NBLK;   // E
    int* bpair         = col + E;                       // E

    // --- CSR build (zero global atomics, fully parallel scan) ---
    k_hist <<<dim3(NBLK),      dim3(256), 0, stream>>>(dst, part, E);
    k_scanA<<<dim3(NBUCK / 4), dim3(256), 0, stream>>>(part, btot);
    k_scanB<<<dim3(1),         dim3(NBUCK), 0, stream>>>(btot, bbase, rowptr, n, E);
    k_binA2<<<dim3(NBLK),      dim3(512), 0, stream>>>(src, dst, part, bbase, bpair, E);
    k_fill2<<<dim3(nbuck),     dim3(512), 0, stream>>>(bpair, bbase, x, rowptr, dis, xs16, col, n);

    // --- layer 1 (8 nodes/wave, gather + W1 + relu + W2) -> g16 ---
    k_g1b<<<dim3((n + 31) / 32), dim3(256), 0, stream>>>(rowptr, col, (const uint4*)xs16,
                                                         dis, W1, b1, W2, (uint2*)g16, n);

    // --- layer 2 + head (8 nodes/wave, 2 edge slots) ---
    k_g2f<<<dim3((n + 31) / 32), dim3(256), 0, stream>>>(rowptr, col, (const uint4*)g16, dis,
                                                         b2, Wf, bf, out, n);
}